// Round 6
// baseline (234.980 us; speedup 1.0000x reference)
//
#include <hip/hip_runtime.h>
#include <cstddef>

namespace {

constexpr int IMG = 256;
constexpr long long N_ELEM = 16LL * 8 * IMG * IMG;   // 8388608

constexpr float RP   = 3.9f;
constexpr float EPSF = 0.3f;
constexpr float OME  = 0.7f;
constexpr float BET  = 0.15f;
constexpr float OMB  = 0.85f;
constexpr float CLO  = 1e-4f;
constexpr float CHI  = (float)(1.0 - 1e-4);

__device__ __forceinline__ float mapf(float g) {
#pragma clang fp contract(off)
    float t = RP * g;          // match numpy op order: (R*g) * (1-g)
    float m = t * (1.0f - g);
    return m;
}

template<bool CX>
__device__ __forceinline__ float4 load4yx(const float* __restrict__ im, int y, int x) {
    bool v = ((unsigned)y < (unsigned)IMG);
    if (CX) v = v && ((unsigned)x < (unsigned)IMG);
    const float* p = im + (v ? (y * IMG + x) : 0);
    float4 r = *(const float4*)p;
    if (!v) { r.x = 0.f; r.y = 0.f; r.z = 0.f; r.w = 0.f; }
    return r;
}

// read MAPPED row r: own quad via ds_read_b128, halos via lane shuffles.
// Wrong-row shuffle data lands only in dead validity margins; wave-boundary
// lanes with a live halo (fixL/fixR) take a 1-lane LDS read.
template<int STR>
__device__ __forceinline__ void loadrow(const float* __restrict__ buf, int r, int c4,
                                        bool fixL, bool fixR, float w[6]) {
    const float* p = buf + r * STR + c4;
    float4 m = *(const float4*)p;   // ds_read_b128
    w[1] = m.x; w[2] = m.y; w[3] = m.z; w[4] = m.w;
    w[0] = __shfl_up(m.w, 1);
    w[5] = __shfl_down(m.x, 1);
    if (fixL) w[0] = p[-1];
    if (fixR) w[5] = p[4];
}

__device__ __forceinline__ float conv3(const float k[9], const float A[6], const float B[6],
                                       const float C[6], int j) {
    float a = k[0] * A[j];
    a = fmaf(k[1], A[j + 1], a);
    a = fmaf(k[2], A[j + 2], a);
    a = fmaf(k[3], B[j],     a);
    a = fmaf(k[4], B[j + 1], a);
    a = fmaf(k[5], B[j + 2], a);
    a = fmaf(k[6], C[j],     a);
    a = fmaf(k[7], C[j + 1], a);
    a = fmaf(k[8], C[j + 2], a);
    return a;
}

// one output row: A = mapped row r-1, B = row r, C = row r+1 (loaded here).
// Output STAGED into registers; LDS write after barrier.
// F: final step -> stage raw g; else stage mapf(g)
#define ROW_BODY(i, A, B, C, F, STR) {                                           \
    loadrow<STR>(buf, start + (i) + 1, c4, fixL, fixR, C);                       \
    const float lv_ = livef[i];                                                  \
    float go_[4];                                                                \
    _Pragma("unroll")                                                            \
    for (int j = 0; j < 4; ++j) {                                                \
        float a_  = conv3(k, A, B, C, j);                                        \
        float ph_ = fmaf(EPSF, a_, OME * B[j + 1]);                              \
        float g_  = fmaf(BET, dv[(i) * 4 + j], OMB * ph_);                       \
        g_ = fminf(fmaxf(g_, CLO), CHI);                                         \
        g_ = g_ * lv_;                                                           \
        sum[(i) * 4 + j] += g_;                                                  \
        sq[(i) * 4 + j]  = fmaf(g_, g_, sq[(i) * 4 + j]);                        \
        if (F) go_[j] = g_; else go_[j] = mapf(g_);                              \
    }                                                                            \
    stg[i].x = go_[0]; stg[i].y = go_[1]; stg[i].z = go_[2]; stg[i].w = go_[3];  \
}

#define STEP5(F, STR) {                                                          \
    float w0[6], w1[6], w2[6];                                                   \
    loadrow<STR>(buf, start - 1, c4, fixL, fixR, w0);                            \
    loadrow<STR>(buf, start,     c4, fixL, fixR, w1);                            \
    ROW_BODY(0, w0, w1, w2, F, STR)                                              \
    ROW_BODY(1, w1, w2, w0, F, STR)                                              \
    ROW_BODY(2, w2, w0, w1, F, STR)                                              \
    ROW_BODY(3, w0, w1, w2, F, STR)                                              \
    ROW_BODY(4, w1, w2, w0, F, STR)                                              \
}

#define STEP4(F, STR) {                                                          \
    float w0[6], w1[6], w2[6];                                                   \
    loadrow<STR>(buf, start - 1, c4, fixL, fixR, w0);                            \
    loadrow<STR>(buf, start,     c4, fixL, fixR, w1);                            \
    ROW_BODY(0, w0, w1, w2, F, STR)                                              \
    ROW_BODY(1, w1, w2, w0, F, STR)                                              \
    ROW_BODY(2, w2, w0, w1, F, STR)                                              \
    ROW_BODY(3, w0, w1, w2, F, STR)                                              \
}

// ================= two-phase kernels (8 + 7 steps, 64x64 tiles, halo 8) =====

constexpr int P_BSTR  = 84;              // 84%32=20, gcd(21,32)=1 -> banks rotate
constexpr int P_BROWS = 82;              // rows 0..81 (80,81 zeroed)
constexpr int P_BUFSZ = P_BROWS * P_BSTR;// 6888 floats = 27552 B
constexpr int P_NTHR  = 320;             // 5 waves
constexpr int P_NCG   = 20;              // 20 col-groups * 4 = 80 cols
constexpr int P_STRIP = 5;               // 16 teams * 5 = rows 1..80

template<bool FIRST, bool EX>
__device__ __forceinline__ void run_tile_p(const float* __restrict__ drive,
                                           const float* __restrict__ Kl,
                                           float* __restrict__ out,
                                           float* __restrict__ ws,
                                           int img, int ty, int tx, float* buf)
{
    const int tid = threadIdx.x;
    const int cg  = (int)((unsigned)tid % (unsigned)P_NCG);
    const int rt  = (int)((unsigned)tid / (unsigned)P_NCG);
    const int c4  = cg * 4;
    const int start = 1 + rt * P_STRIP;
    const int lane = tid & 63;
    const bool fixL = (lane == 0)  && (cg != 0);
    const bool fixR = (lane == 63) && (cg != P_NCG - 1);

    const int ch = img & 7;
    float k[9];
#pragma unroll
    for (int i = 0; i < 9; ++i) k[i] = Kl[ch * 9 + i];

    const float* dimg = drive + (size_t)img * (IMG * IMG);
    const float* simg = FIRST ? dimg : (ws + (size_t)img * (IMG * IMG));
    const int y0 = ty * 64 - 8;
    const int x0 = tx * 64 - 8;
    const int xg = x0 + c4;
    const bool xok = ((unsigned)xg < (unsigned)IMG);

    // ---- stage rows 0..79: mapped field (phase1: drive, phase2: g8 from ws)
#pragma unroll
    for (int it = 0; it < 5; ++it) {
        int task = tid + it * P_NTHR;            // 0..1599 exactly
        int r = (int)((unsigned)task / (unsigned)P_NCG);
        int c = (int)((unsigned)task % (unsigned)P_NCG) * 4;
        float4 v = load4yx<EX>(simg, y0 + r, x0 + c);
        float4 m; m.x = mapf(v.x); m.y = mapf(v.y); m.z = mapf(v.z); m.w = mapf(v.w);
        *(float4*)(buf + r * P_BSTR + c) = m;
    }
    if (tid < 2 * P_NCG) {                        // zero rows 80,81
        int r = 80 + tid / P_NCG;
        int c = (tid % P_NCG) * 4;
        float4 z; z.x = 0.f; z.y = 0.f; z.z = 0.f; z.w = 0.f;
        *(float4*)(buf + r * P_BSTR + c) = z;
    }

    // ---- own drive pixels + liveness -> registers
    float dv[P_STRIP * 4];
    float livef[P_STRIP];
#pragma unroll
    for (int i = 0; i < P_STRIP; ++i) {
        const int y = y0 + start + i;
        bool ok = ((unsigned)y < (unsigned)IMG);
        if (EX) ok = ok && xok;
        livef[i] = ok ? 1.0f : 0.0f;
        float4 t = load4yx<EX>(dimg, y, xg);
        dv[i * 4 + 0] = t.x; dv[i * 4 + 1] = t.y;
        dv[i * 4 + 2] = t.z; dv[i * 4 + 3] = t.w;
    }

    float sum[P_STRIP * 4], sq[P_STRIP * 4];
#pragma unroll
    for (int i = 0; i < P_STRIP * 4; ++i) { sum[i] = 0.f; sq[i] = 0.f; }

    float4 stg[P_STRIP];

    __syncthreads();

    const int NS = FIRST ? 8 : 7;
    for (int s = 0; s < NS - 1; ++s) {
        STEP5(0, P_BSTR)
        __syncthreads();
#pragma unroll
        for (int i = 0; i < P_STRIP; ++i)
            *(float4*)(buf + (start + i) * P_BSTR + c4) = stg[i];
        __syncthreads();
    }
    STEP5(1, P_BSTR)   // final step of this phase: raw g stays in stg

    // ---- epilogue
    const bool colin = (c4 >= 8) && (c4 <= 68);
    const float inv15 = 1.0f / 15.0f;

#pragma unroll
    for (int i = 0; i < P_STRIP; ++i) {
        const int r = start + i;
        const bool rowin = (r >= 8) && (r <= 71);
        if (colin && rowin) {
            const int y = y0 + r;
            size_t base = (size_t)img * (IMG * IMG) + (size_t)y * IMG + xg;
            if (FIRST) {
                *(float4*)(ws + base) = stg[i];                  // g8 checkpoint
                float4 s4; s4.x = sum[i*4+0]; s4.y = sum[i*4+1]; s4.z = sum[i*4+2]; s4.w = sum[i*4+3];
                float4 q4; q4.x = sq[i*4+0];  q4.y = sq[i*4+1];  q4.z = sq[i*4+2];  q4.w = sq[i*4+3];
                *(float4*)(out + 1 * N_ELEM + base) = s4;        // partial sum
                *(float4*)(out + 2 * N_ELEM + base) = q4;        // partial sq
            } else {
                float4 ps4 = *(const float4*)(out + 1 * N_ELEM + base);
                float4 pq4 = *(const float4*)(out + 2 * N_ELEM + base);
                float ps[4] = {ps4.x, ps4.y, ps4.z, ps4.w};
                float pq[4] = {pq4.x, pq4.y, pq4.z, pq4.w};
                float gg[4] = {stg[i].x, stg[i].y, stg[i].z, stg[i].w};
                float mn[4], vr[4], dl[4];
#pragma unroll
                for (int j = 0; j < 4; ++j) {
                    float st = ps[j] + sum[i * 4 + j];
                    float qt = pq[j] + sq[i * 4 + j];
                    float m = st * inv15;
                    float v = fmaf(-m, m, qt * inv15);
                    vr[j] = fmaxf(v, 0.0f);
                    mn[j] = m;
                    dl[j] = gg[j] - dv[i * 4 + j];
                }
                float4 g4; g4.x = gg[0]; g4.y = gg[1]; g4.z = gg[2]; g4.w = gg[3];
                float4 m4; m4.x = mn[0]; m4.y = mn[1]; m4.z = mn[2]; m4.w = mn[3];
                float4 v4; v4.x = vr[0]; v4.y = vr[1]; v4.z = vr[2]; v4.w = vr[3];
                float4 d4; d4.x = dl[0]; d4.y = dl[1]; d4.z = dl[2]; d4.w = dl[3];
                *(float4*)(out + 0 * N_ELEM + base) = g4;   // last
                *(float4*)(out + 1 * N_ELEM + base) = m4;   // mean
                *(float4*)(out + 2 * N_ELEM + base) = v4;   // var
                *(float4*)(out + 3 * N_ELEM + base) = d4;   // delta
                *(float4*)(out + 4 * N_ELEM + base) = d4;   // last_drive
            }
        }
    }
}

template<bool FIRST>
__global__ __launch_bounds__(P_NTHR, 4)
void cml_phase(const float* __restrict__ drive, const float* __restrict__ Kl,
               float* __restrict__ out, float* __restrict__ ws)
{
    __shared__ __align__(16) float lds[P_BUFSZ + 8];   // 27584 B
    const int bx  = blockIdx.x;
    const int img = bx >> 4;         // 0..127
    const int t   = bx & 15;
    const int ty  = t >> 2;          // 0..3
    const int tx  = t & 3;           // 0..3
    const bool ex = (tx == 0) | (tx == 3);
    if (ex) run_tile_p<FIRST, true >(drive, Kl, out, ws, img, ty, tx, lds);
    else    run_tile_p<FIRST, false>(drive, Kl, out, ws, img, ty, tx, lds);
}

// ================= fallback: proven single-phase R5 kernel ==================

constexpr int F_TILE_R = 128;
constexpr int F_BSTR   = 100;
constexpr int F_BROWS  = 162;
constexpr int F_BUFSZ  = F_BROWS * F_BSTR;
constexpr int F_NTHR   = 960;
constexpr int F_NCG    = 24;
constexpr int F_STRIP  = 4;
constexpr int F_SROWS  = 159;

template<bool EX>
__device__ __forceinline__ void run_tile_fb(const float* __restrict__ drive,
                                            const float* __restrict__ Kl,
                                            float* __restrict__ out,
                                            int img, int ty, int tx, float* buf)
{
    const int tid = threadIdx.x;
    const int cg  = (int)((unsigned)tid % (unsigned)F_NCG);
    const int rt  = (int)((unsigned)tid / (unsigned)F_NCG);
    const int c4  = cg * 4;
    const int start = 1 + rt * F_STRIP;
    const int lane = tid & 63;
    const bool fixL = (lane == 0)  && (cg != 0);
    const bool fixR = (lane == 63) && (cg != 23);

    const int ch = img & 7;
    float k[9];
#pragma unroll
    for (int i = 0; i < 9; ++i) k[i] = Kl[ch * 9 + i];

    const float* dimg = drive + (size_t)img * (IMG * IMG);
    const int y0 = ty * F_TILE_R - 16;
    const int x0 = tx * 64 - 16;
    const int xg = x0 + c4;
    const bool xok = ((unsigned)xg < (unsigned)IMG);

#pragma unroll
    for (int it = 0; it < 4; ++it) {
        int task = tid + it * F_NTHR;
        if (task < F_SROWS * F_NCG) {
            int r = (int)((unsigned)task / (unsigned)F_NCG);
            int c = (int)((unsigned)task % (unsigned)F_NCG) * 4;
            float4 v = load4yx<EX>(dimg, y0 + r, x0 + c);
            float4 m; m.x = mapf(v.x); m.y = mapf(v.y); m.z = mapf(v.z); m.w = mapf(v.w);
            *(float4*)(buf + r * F_BSTR + c) = m;
        }
    }

    float dv[F_STRIP * 4];
    float livef[F_STRIP];
#pragma unroll
    for (int i = 0; i < F_STRIP; ++i) {
        const int y = y0 + start + i;
        bool ok = ((unsigned)y < (unsigned)IMG);
        if (EX) ok = ok && xok;
        livef[i] = ok ? 1.0f : 0.0f;
        float4 t = load4yx<EX>(dimg, y, xg);
        dv[i * 4 + 0] = t.x; dv[i * 4 + 1] = t.y;
        dv[i * 4 + 2] = t.z; dv[i * 4 + 3] = t.w;
    }

    float sum[F_STRIP * 4], sq[F_STRIP * 4];
#pragma unroll
    for (int i = 0; i < F_STRIP * 4; ++i) { sum[i] = 0.f; sq[i] = 0.f; }

    float4 stg[F_STRIP];

    __syncthreads();

    for (int s = 0; s < 14; ++s) {
        STEP4(0, F_BSTR)
        __syncthreads();
#pragma unroll
        for (int i = 0; i < F_STRIP; ++i)
            *(float4*)(buf + (start + i) * F_BSTR + c4) = stg[i];
        __syncthreads();
    }
    STEP4(1, F_BSTR)

    const bool colin = (c4 >= 16) && (c4 <= 76);
    const float inv15 = 1.0f / 15.0f;

#pragma unroll
    for (int i = 0; i < F_STRIP; ++i) {
        const int r = start + i;
        const bool rowin = (r >= 16) && (r <= 16 + F_TILE_R - 1);
        if (colin && rowin) {
            const int y = y0 + r;
            float gg[4] = {stg[i].x, stg[i].y, stg[i].z, stg[i].w};
            float mn[4], vr[4], dl[4];
#pragma unroll
            for (int j = 0; j < 4; ++j) {
                float m = sum[i * 4 + j] * inv15;
                float v = fmaf(-m, m, sq[i * 4 + j] * inv15);
                vr[j] = fmaxf(v, 0.0f);
                mn[j] = m;
                dl[j] = gg[j] - dv[i * 4 + j];
            }
            size_t base = (size_t)img * (IMG * IMG) + (size_t)y * IMG + xg;
            float4 g4; g4.x = gg[0]; g4.y = gg[1]; g4.z = gg[2]; g4.w = gg[3];
            float4 m4; m4.x = mn[0]; m4.y = mn[1]; m4.z = mn[2]; m4.w = mn[3];
            float4 v4; v4.x = vr[0]; v4.y = vr[1]; v4.z = vr[2]; v4.w = vr[3];
            float4 d4; d4.x = dl[0]; d4.y = dl[1]; d4.z = dl[2]; d4.w = dl[3];
            *(float4*)(out + 0 * N_ELEM + base) = g4;
            *(float4*)(out + 1 * N_ELEM + base) = m4;
            *(float4*)(out + 2 * N_ELEM + base) = v4;
            *(float4*)(out + 3 * N_ELEM + base) = d4;
            *(float4*)(out + 4 * N_ELEM + base) = d4;
        }
    }
}

__global__ __launch_bounds__(F_NTHR, 4)
void cml_fb(const float* __restrict__ drive, const float* __restrict__ Kl,
            float* __restrict__ out)
{
    __shared__ __align__(16) float lds[F_BUFSZ + 8];
    const int bx  = blockIdx.x;
    const int img = bx >> 3;
    const int t   = bx & 7;
    const int ty  = t >> 2;
    const int tx  = t & 3;
    const bool ex = (tx == 0) | (tx == 3);
    if (ex) run_tile_fb<true >(drive, Kl, out, img, ty, tx, lds);
    else    run_tile_fb<false>(drive, Kl, out, img, ty, tx, lds);
}

} // namespace

extern "C" void kernel_launch(void* const* d_in, const int* in_sizes, int n_in,
                              void* d_out, int out_size, void* d_ws, size_t ws_size,
                              hipStream_t stream) {
    const float* drive = (const float*)d_in[0];
    const float* Kl    = (const float*)d_in[1];
    float* out         = (float*)d_out;
    (void)in_sizes; (void)n_in; (void)out_size;

    const size_t need = (size_t)N_ELEM * sizeof(float);   // 33.5 MB g8 checkpoint
    if (ws_size >= need) {
        float* ws = (float*)d_ws;
        cml_phase<true ><<<dim3(128 * 16), dim3(P_NTHR), 0, stream>>>(drive, Kl, out, ws);
        cml_phase<false><<<dim3(128 * 16), dim3(P_NTHR), 0, stream>>>(drive, Kl, out, ws);
    } else {
        cml_fb<<<dim3(128 * 8), dim3(F_NTHR), 0, stream>>>(drive, Kl, out);
    }
}

// Round 7
// 157.302 us; speedup vs baseline: 1.4938x; 1.4938x over previous
//
#include <hip/hip_runtime.h>
#include <cstddef>

namespace {

constexpr int IMG = 256;
constexpr long long N_ELEM = 16LL * 8 * IMG * IMG;   // 8388608

constexpr int NTHR   = 768;            // 12 waves
constexpr int NCG    = 24;             // 24 col-groups * 4 cols = 96 buffer cols
constexpr int NW     = 12;             // waves per block
constexpr int DSTR   = 100;            // boundary-row stride (floats); %32==4 -> bank rotation
constexpr int DSLOTS = 66;             // slots: 0..65 (slot 2t+1 = team t row start, 2t+2 = row start+4)
constexpr int DBUF   = DSLOTS * DSTR;  // 6600 floats per buffer
constexpr int XSTR   = 16;             // per-wave X record (floats): [0..4]=lane63 .w, [8..12]=lane0 .x
constexpr int XBUF   = NW * XSTR;      // 192 floats per buffer

constexpr float RP   = 3.9f;
constexpr float EPSF = 0.3f;
constexpr float OME  = 0.7f;    // 1 - EPS
constexpr float BET  = 0.15f;
constexpr float OMB  = 0.85f;   // 1 - BETA
constexpr float CLO  = 1e-4f;
constexpr float CHI  = (float)(1.0 - 1e-4);

__device__ __forceinline__ float mapf(float g) {
#pragma clang fp contract(off)
    float t = RP * g;          // match numpy op order: (R*g) * (1-g)
    float m = t * (1.0f - g);
    return m;
}

template<bool CX>
__device__ __forceinline__ float4 load4yx(const float* __restrict__ im, int y, int x) {
    bool v = ((unsigned)y < (unsigned)IMG);
    if (CX) v = v && ((unsigned)x < (unsigned)IMG);
    const float* p = im + (v ? (y * IMG + x) : 0);
    float4 r = *(const float4*)p;
    if (!v) { r.x = 0.f; r.y = 0.f; r.z = 0.f; r.w = 0.f; }
    return r;
}

__device__ __forceinline__ float px9(const float k[9],
        float a0, float a1, float a2, float b0, float b1, float b2,
        float c0, float c1, float c2, float dvv, float lv) {
    float a = k[0] * a0;
    a = fmaf(k[1], a1, a); a = fmaf(k[2], a2, a);
    a = fmaf(k[3], b0, a); a = fmaf(k[4], b1, a); a = fmaf(k[5], b2, a);
    a = fmaf(k[6], c0, a); a = fmaf(k[7], c1, a); a = fmaf(k[8], c2, a);
    float ph = fmaf(EPSF, a, OME * b1);
    float g  = fmaf(BET, dvv, OMB * ph);
    g = fminf(fmaxf(g, CLO), CHI);
    return g * lv;
}

// build a 6-wide window from a row quad: own 4 + shuffle halos + masked fixups
#define WINQ(W, QX, QY, QZ, QW, VL, VR) {      \
    W[1] = (QX); W[2] = (QY); W[3] = (QZ); W[4] = (QW); \
    W[0] = __shfl_up((QW), 1);                 \
    W[5] = __shfl_down((QX), 1);               \
    if (fixL) W[0] = (VL);                     \
    if (fixR) W[5] = (VR);                     \
}

// one output row from windows WA(r-1), WB(r), WC(r+1); updates stats, stg in place
#define ROWB(WA, WB, WC, DV, LV, SUM, SQ, STG, F) {                                        \
    float g0 = px9(k, WA[0],WA[1],WA[2], WB[0],WB[1],WB[2], WC[0],WC[1],WC[2], DV.x, LV);  \
    float g1 = px9(k, WA[1],WA[2],WA[3], WB[1],WB[2],WB[3], WC[1],WC[2],WC[3], DV.y, LV);  \
    float g2 = px9(k, WA[2],WA[3],WA[4], WB[2],WB[3],WB[4], WC[2],WC[3],WC[4], DV.z, LV);  \
    float g3 = px9(k, WA[3],WA[4],WA[5], WB[3],WB[4],WB[5], WC[3],WC[4],WC[5], DV.w, LV);  \
    SUM.x += g0; SUM.y += g1; SUM.z += g2; SUM.w += g3;                                    \
    SQ.x = fmaf(g0,g0,SQ.x); SQ.y = fmaf(g1,g1,SQ.y);                                      \
    SQ.z = fmaf(g2,g2,SQ.z); SQ.w = fmaf(g3,g3,SQ.w);                                      \
    if (F) { STG.x = g0; STG.y = g1; STG.z = g2; STG.w = g3; }                             \
    else   { STG.x = mapf(g0); STG.y = mapf(g1); STG.z = mapf(g2); STG.w = mapf(g3); }     \
}

// one timestep: read boundary rows/fix cols from (DR,XR), compute 5 rows in regs,
// write new boundary rows/fix cols to (DW,XW_), one barrier.  F=1: final (no writes)
#define STEP(F, DR, DW, XR, XW_) {                                              \
    float xl0=0,xl1=0,xl2=0,xl3=0,xl4=0, xr0=0,xr1=0,xr2=0,xr3=0,xr4=0;         \
    float dfl0=0,dfl5=0,dfr0=0,dfr5=0;                                          \
    if (fixL) { const float* xp = (XR) + (wv-1)*XSTR;                           \
        float4 a = *(const float4*)xp; xl0=a.x; xl1=a.y; xl2=a.z; xl3=a.w;      \
        xl4 = xp[4];                                                            \
        dfl0 = (DR)[slotL*DSTR + c4 - 1]; dfl5 = (DR)[slotR*DSTR + c4 - 1]; }   \
    if (fixR) { const float* xp = (XR) + (wv+1)*XSTR + 8;                       \
        float4 a = *(const float4*)xp; xr0=a.x; xr1=a.y; xr2=a.z; xr3=a.w;      \
        xr4 = xp[4];                                                            \
        dfr0 = (DR)[slotL*DSTR + c4 + 4]; dfr5 = (DR)[slotR*DSTR + c4 + 4]; }   \
    float4 qL = *(const float4*)((DR) + slotL*DSTR + c4);                       \
    float4 qR = *(const float4*)((DR) + slotR*DSTR + c4);                       \
    float wA[6], wB[6], wC[6];                                                  \
    WINQ(wA, qL.x, qL.y, qL.z, qL.w, dfl0, dfr0)                                \
    WINQ(wB, stg0.x, stg0.y, stg0.z, stg0.w, xl0, xr0)                          \
    WINQ(wC, stg1.x, stg1.y, stg1.z, stg1.w, xl1, xr1)                          \
    ROWB(wA, wB, wC, dv0, lv0, sum0, sq0, stg0, F)                              \
    if (!(F)) *(float4*)((DW) + (2*rt+1)*DSTR + c4) = stg0;                     \
    WINQ(wA, stg2.x, stg2.y, stg2.z, stg2.w, xl2, xr2)                          \
    ROWB(wB, wC, wA, dv1, lv1, sum1, sq1, stg1, F)                              \
    WINQ(wB, stg3.x, stg3.y, stg3.z, stg3.w, xl3, xr3)                          \
    ROWB(wC, wA, wB, dv2, lv2, sum2, sq2, stg2, F)                              \
    WINQ(wC, stg4.x, stg4.y, stg4.z, stg4.w, xl4, xr4)                          \
    ROWB(wA, wB, wC, dv3, lv3, sum3, sq3, stg3, F)                              \
    WINQ(wA, qR.x, qR.y, qR.z, qR.w, dfl5, dfr5)                                \
    ROWB(wB, wC, wA, dv4, lv4, sum4, sq4, stg4, F)                              \
    if (!(F)) {                                                                 \
        *(float4*)((DW) + (2*rt+2)*DSTR + c4) = stg4;                           \
        if (lane == 63) { float4 a; a.x=stg0.w; a.y=stg1.w; a.z=stg2.w; a.w=stg3.w; \
            *(float4*)((XW_) + wv*XSTR) = a; (XW_)[wv*XSTR + 4] = stg4.w; }     \
        if (lane == 0)  { float4 a; a.x=stg0.x; a.y=stg1.x; a.z=stg2.x; a.w=stg3.x; \
            *(float4*)((XW_) + wv*XSTR + 8) = a; (XW_)[wv*XSTR + 12] = stg4.x; }\
        __syncthreads();                                                        \
    }                                                                           \
}

template<bool EX>
__device__ __forceinline__ void run_tile(const float* __restrict__ drive,
                                         const float* __restrict__ Kl,
                                         float* __restrict__ out,
                                         int img, int ty, int tx,
                                         float* __restrict__ lds)
{
    float* Da = lds;
    float* Db = lds + DBUF;
    float* Xa = lds + 2 * DBUF;
    float* Xb = Xa + XBUF;

    const int tid = threadIdx.x;
    const int cg  = (int)((unsigned)tid % (unsigned)NCG);
    const int rt  = (int)((unsigned)tid / (unsigned)NCG);   // 0..31, rows start..start+4
    const int c4  = cg * 4;
    const int start = 1 + rt * 5;
    const int lane = tid & 63;
    const int wv   = tid >> 6;
    const bool fixL = (lane == 0)  && (cg != 0);
    const bool fixR = (lane == 63) && (cg != NCG - 1);
    const int slotL = 2 * rt;        // row start-1 (team t-1's row start+4)
    const int slotR = 2 * rt + 3;    // row start+5 (team t+1's row start)

    const int ch = img & 7;
    float k[9];
#pragma unroll
    for (int i = 0; i < 9; ++i) k[i] = Kl[ch * 9 + i];

    const float* dimg = drive + (size_t)img * (IMG * IMG);
    const int y0 = ty * 128 - 16;
    const int x0 = tx * 64 - 16;
    const int xg = x0 + c4;
    const bool xok = ((unsigned)xg < (unsigned)IMG);

    float4 dv0,dv1,dv2,dv3,dv4, stg0,stg1,stg2,stg3,stg4;
    float4 sum0,sum1,sum2,sum3,sum4, sq0,sq1,sq2,sq3,sq4;
    float  lv0,lv1,lv2,lv3,lv4;

#define INITROW(I) { int y = y0 + start + (I);                                   \
    bool ok = ((unsigned)y < (unsigned)IMG); if (EX) ok = ok && xok;             \
    lv##I = ok ? 1.0f : 0.0f;                                                    \
    dv##I = load4yx<EX>(dimg, y, xg);                                            \
    stg##I.x = mapf(dv##I.x); stg##I.y = mapf(dv##I.y);                          \
    stg##I.z = mapf(dv##I.z); stg##I.w = mapf(dv##I.w);                          \
    sum##I.x = 0.f; sum##I.y = 0.f; sum##I.z = 0.f; sum##I.w = 0.f;              \
    sq##I = sum##I; }
    INITROW(0) INITROW(1) INITROW(2) INITROW(3) INITROW(4)
#undef INITROW

    // ---- init boundary buffers (buffer A) + zero pad slots of both buffers
    *(float4*)(Da + (2*rt+1)*DSTR + c4) = stg0;
    *(float4*)(Da + (2*rt+2)*DSTR + c4) = stg4;
    if (rt == 0) {
        float4 z; z.x = 0.f; z.y = 0.f; z.z = 0.f; z.w = 0.f;
        *(float4*)(Da + 0  * DSTR + c4) = z;
        *(float4*)(Da + 65 * DSTR + c4) = z;
        *(float4*)(Db + 0  * DSTR + c4) = z;
        *(float4*)(Db + 65 * DSTR + c4) = z;
    }
    if (lane == 63) { float4 a; a.x=stg0.w; a.y=stg1.w; a.z=stg2.w; a.w=stg3.w;
        *(float4*)(Xa + wv*XSTR) = a; Xa[wv*XSTR + 4] = stg4.w; }
    if (lane == 0)  { float4 a; a.x=stg0.x; a.y=stg1.x; a.z=stg2.x; a.w=stg3.x;
        *(float4*)(Xa + wv*XSTR + 8) = a; Xa[wv*XSTR + 12] = stg4.x; }
    __syncthreads();

    // ---- 14 full steps (buffer ping-pong, ONE barrier each) + final step
#pragma unroll 1
    for (int s2 = 0; s2 < 7; ++s2) {
        STEP(0, Da, Db, Xa, Xb)
        STEP(0, Db, Da, Xb, Xa)
    }
    STEP(1, Da, Db, Xa, Xb)

    // ---- epilogue (all in registers)
    const float inv15 = 1.0f / 15.0f;
    const bool colin = (c4 >= 16) && (c4 <= 76);

#define EPI(I) { const int r = start + (I);                                       \
    if (colin && r >= 16 && r <= 143) {                                           \
        const int y = y0 + r;                                                     \
        size_t base = (size_t)img * (IMG*IMG) + (size_t)y * IMG + xg;             \
        float mn0 = sum##I.x*inv15, mn1 = sum##I.y*inv15;                         \
        float mn2 = sum##I.z*inv15, mn3 = sum##I.w*inv15;                         \
        float4 m4; m4.x=mn0; m4.y=mn1; m4.z=mn2; m4.w=mn3;                        \
        float4 v4;                                                               \
        v4.x = fmaxf(fmaf(-mn0, mn0, sq##I.x*inv15), 0.f);                        \
        v4.y = fmaxf(fmaf(-mn1, mn1, sq##I.y*inv15), 0.f);                        \
        v4.z = fmaxf(fmaf(-mn2, mn2, sq##I.z*inv15), 0.f);                        \
        v4.w = fmaxf(fmaf(-mn3, mn3, sq##I.w*inv15), 0.f);                        \
        float4 d4; d4.x = stg##I.x - dv##I.x; d4.y = stg##I.y - dv##I.y;          \
        d4.z = stg##I.z - dv##I.z; d4.w = stg##I.w - dv##I.w;                     \
        *(float4*)(out + 0*N_ELEM + base) = stg##I;                               \
        *(float4*)(out + 1*N_ELEM + base) = m4;                                   \
        *(float4*)(out + 2*N_ELEM + base) = v4;                                   \
        *(float4*)(out + 3*N_ELEM + base) = d4;                                   \
        *(float4*)(out + 4*N_ELEM + base) = d4; } }
    EPI(0) EPI(1) EPI(2) EPI(3) EPI(4)
#undef EPI
}

__global__ __launch_bounds__(NTHR, 3)   // 3 waves/EU -> VGPR cap ~170, 1 WG of 12 waves
void cml_kernel(const float* __restrict__ drive,
                const float* __restrict__ Kl,
                float* __restrict__ out)
{
    __shared__ __align__(16) float lds[2 * DBUF + 2 * XBUF];   // 54336 B
    const int bx  = blockIdx.x;
    const int img = bx >> 3;         // 0..127  (b*8 + c)
    const int t   = bx & 7;
    const int ty  = t >> 2;          // 0..1  (128-row tiles)
    const int tx  = t & 3;           // 0..3  (64-col tiles)
    const bool ex = (tx == 0) | (tx == 3);
    if (ex) run_tile<true >(drive, Kl, out, img, ty, tx, lds);
    else    run_tile<false>(drive, Kl, out, img, ty, tx, lds);
}

} // namespace

extern "C" void kernel_launch(void* const* d_in, const int* in_sizes, int n_in,
                              void* d_out, int out_size, void* d_ws, size_t ws_size,
                              hipStream_t stream) {
    const float* drive = (const float*)d_in[0];
    const float* Kl    = (const float*)d_in[1];
    float* out         = (float*)d_out;
    (void)in_sizes; (void)n_in; (void)out_size; (void)d_ws; (void)ws_size;

    dim3 grid(128 * 8);   // 128 images * 8 tiles (128x64)
    dim3 block(NTHR);
    cml_kernel<<<grid, block, 0, stream>>>(drive, Kl, out);
}

// Round 8
// 129.464 us; speedup vs baseline: 1.8150x; 1.2150x over previous
//
#include <hip/hip_runtime.h>
#include <cstddef>

namespace {

constexpr int IMG = 256;
constexpr long long N_ELEM = 16LL * 8 * IMG * IMG;   // 8388608

constexpr int NTHR   = 768;            // 12 waves = 12 row-teams
constexpr int NW     = 12;
constexpr int STRIP  = 8;              // rows per thread; 12*8 = 96 compute rows
constexpr int DSTR   = 256;            // boundary row stride = full width (wave-linear, conflict-free)
constexpr int DSLOTS = 26;             // 2 per team + zero slots 0 and 25
constexpr int DBUF   = DSLOTS * DSTR;  // 6656 floats per buffer

constexpr float RP   = 3.9f;
constexpr float EPSF = 0.3f;
constexpr float OME  = 0.7f;    // 1 - EPS
constexpr float BET  = 0.15f;
constexpr float OMB  = 0.85f;   // 1 - BETA
constexpr float CLO  = 1e-4f;
constexpr float CHI  = (float)(1.0 - 1e-4);

__device__ __forceinline__ float mapf(float g) {
#pragma clang fp contract(off)
    float t = RP * g;          // match numpy op order: (R*g) * (1-g)
    float m = t * (1.0f - g);
    return m;
}

__device__ __forceinline__ float px9(const float k[9],
        float a0, float a1, float a2, float b0, float b1, float b2,
        float c0, float c1, float c2, float dvv) {
    float a = k[0] * a0;
    a = fmaf(k[1], a1, a); a = fmaf(k[2], a2, a);
    a = fmaf(k[3], b0, a); a = fmaf(k[4], b1, a); a = fmaf(k[5], b2, a);
    a = fmaf(k[6], c0, a); a = fmaf(k[7], c1, a); a = fmaf(k[8], c2, a);
    float ph = fmaf(EPSF, a, OME * b1);
    float g  = fmaf(BET, dvv, OMB * ph);
    g = fminf(fmaxf(g, CLO), CHI);
    return g;
}

// 6-wide window from a full-width row quad: halos via intra-wave shfl;
// lane 0 / lane 63 edges are the REAL image zero-padding -> constant 0.
#define WINQ(W, QX, QY, QZ, QW) {                       \
    W[1] = (QX); W[2] = (QY); W[3] = (QZ); W[4] = (QW); \
    W[0] = __shfl_up((QW), 1);                          \
    W[5] = __shfl_down((QX), 1);                        \
    if (lane == 0)  W[0] = 0.0f;                        \
    if (lane == 63) W[5] = 0.0f;                        \
}

// one output row I from windows WA(r-1), WB(r), WC(r+1); stats + stg in place.
// EY (template param in scope): multiply by row liveness after clamp.
#define ROWB(WA, WB, WC, I, F) {                                                           \
    float g0 = px9(k, WA[0],WA[1],WA[2], WB[0],WB[1],WB[2], WC[0],WC[1],WC[2], dv##I.x);   \
    float g1 = px9(k, WA[1],WA[2],WA[3], WB[1],WB[2],WB[3], WC[1],WC[2],WC[3], dv##I.y);   \
    float g2 = px9(k, WA[2],WA[3],WA[4], WB[2],WB[3],WB[4], WC[2],WC[3],WC[4], dv##I.z);   \
    float g3 = px9(k, WA[3],WA[4],WA[5], WB[3],WB[4],WB[5], WC[3],WC[4],WC[5], dv##I.w);   \
    if (EY) { g0 *= lv##I; g1 *= lv##I; g2 *= lv##I; g3 *= lv##I; }                        \
    sum##I.x += g0; sum##I.y += g1; sum##I.z += g2; sum##I.w += g3;                        \
    sq##I.x = fmaf(g0,g0,sq##I.x); sq##I.y = fmaf(g1,g1,sq##I.y);                          \
    sq##I.z = fmaf(g2,g2,sq##I.z); sq##I.w = fmaf(g3,g3,sq##I.w);                          \
    if (F) { stg##I.x = g0; stg##I.y = g1; stg##I.z = g2; stg##I.w = g3; }                 \
    else   { stg##I.x = mapf(g0); stg##I.y = mapf(g1);                                     \
             stg##I.z = mapf(g2); stg##I.w = mapf(g3); }                                   \
}

// one timestep: read 2 boundary rows from DR, compute 8 rows in regs,
// write 2 new boundary rows to DW, one barrier.  F=1: final (no writes/barrier)
#define STEP(F, DR, DW) {                                                       \
    float4 qL = *(const float4*)((DR) + slotL * DSTR + c4);                     \
    float4 qR = *(const float4*)((DR) + slotR * DSTR + c4);                     \
    float wA[6], wB[6], wC[6];                                                  \
    WINQ(wA, qL.x, qL.y, qL.z, qL.w)                                            \
    WINQ(wB, stg0.x, stg0.y, stg0.z, stg0.w)                                    \
    WINQ(wC, stg1.x, stg1.y, stg1.z, stg1.w)                                    \
    ROWB(wA, wB, wC, 0, F)                                                      \
    if (!(F)) *(float4*)((DW) + (2*wv+1) * DSTR + c4) = stg0;                   \
    WINQ(wA, stg2.x, stg2.y, stg2.z, stg2.w)                                    \
    ROWB(wB, wC, wA, 1, F)                                                      \
    WINQ(wB, stg3.x, stg3.y, stg3.z, stg3.w)                                    \
    ROWB(wC, wA, wB, 2, F)                                                      \
    WINQ(wC, stg4.x, stg4.y, stg4.z, stg4.w)                                    \
    ROWB(wA, wB, wC, 3, F)                                                      \
    WINQ(wA, stg5.x, stg5.y, stg5.z, stg5.w)                                    \
    ROWB(wB, wC, wA, 4, F)                                                      \
    WINQ(wB, stg6.x, stg6.y, stg6.z, stg6.w)                                    \
    ROWB(wC, wA, wB, 5, F)                                                      \
    WINQ(wC, stg7.x, stg7.y, stg7.z, stg7.w)                                    \
    ROWB(wA, wB, wC, 6, F)                                                      \
    WINQ(wA, qR.x, qR.y, qR.z, qR.w)                                            \
    ROWB(wB, wC, wA, 7, F)                                                      \
    if (!(F)) {                                                                 \
        *(float4*)((DW) + (2*wv+2) * DSTR + c4) = stg7;                         \
        __syncthreads();                                                        \
    }                                                                           \
}

template<bool EY>
__device__ __forceinline__ void run_tile(const float* __restrict__ drive,
                                         const float* __restrict__ Kl,
                                         float* __restrict__ out,
                                         int img, int ty,
                                         float* __restrict__ lds)
{
    float* Da = lds;
    float* Db = lds + DBUF;

    const int tid  = threadIdx.x;
    const int lane = tid & 63;
    const int wv   = tid >> 6;          // wave = row-team 0..11
    const int c4   = lane * 4;          // own columns c4..c4+3 (full 256 width)
    const int start = wv * STRIP;       // block-relative first row
    const int slotL = 2 * wv;           // row start-1 (team wv-1's last row)
    const int slotR = 2 * wv + 3;       // row start+8 (team wv+1's first row)

    const int ch = img & 7;
    float k[9];
#pragma unroll
    for (int i = 0; i < 9; ++i) k[i] = Kl[ch * 9 + i];   // uniform -> SGPRs

    const float* dimg = drive + (size_t)img * (IMG * IMG);
    const int y0 = ty * 64 - 16;        // image y of block row 0

    float4 dv0,dv1,dv2,dv3,dv4,dv5,dv6,dv7;
    float4 stg0,stg1,stg2,stg3,stg4,stg5,stg6,stg7;
    float4 sum0,sum1,sum2,sum3,sum4,sum5,sum6,sum7;
    float4 sq0,sq1,sq2,sq3,sq4,sq5,sq6,sq7;
    float  lv0,lv1,lv2,lv3,lv4,lv5,lv6,lv7;

#define INITROW(I) {                                                             \
    const int y = y0 + start + (I);                                              \
    if (EY) {                                                                    \
        bool ok = ((unsigned)y < (unsigned)IMG);                                 \
        lv##I = ok ? 1.0f : 0.0f;                                                \
        const float* p = dimg + (ok ? y * IMG + c4 : 0);                         \
        float4 t = *(const float4*)p;                                            \
        if (!ok) { t.x = 0.f; t.y = 0.f; t.z = 0.f; t.w = 0.f; }                 \
        dv##I = t;                                                               \
    } else {                                                                     \
        lv##I = 1.0f;                                                            \
        dv##I = *(const float4*)(dimg + y * IMG + c4);                           \
    }                                                                            \
    stg##I.x = mapf(dv##I.x); stg##I.y = mapf(dv##I.y);                          \
    stg##I.z = mapf(dv##I.z); stg##I.w = mapf(dv##I.w);                          \
    sum##I.x = 0.f; sum##I.y = 0.f; sum##I.z = 0.f; sum##I.w = 0.f;              \
    sq##I = sum##I; }
    INITROW(0) INITROW(1) INITROW(2) INITROW(3)
    INITROW(4) INITROW(5) INITROW(6) INITROW(7)
#undef INITROW
    (void)lv0;

    // ---- init boundary slots (buffer A) + zero slots 0/25 of both buffers
    *(float4*)(Da + (2*wv+1) * DSTR + c4) = stg0;
    *(float4*)(Da + (2*wv+2) * DSTR + c4) = stg7;
    if (wv == 0) {
        float4 z; z.x = 0.f; z.y = 0.f; z.z = 0.f; z.w = 0.f;
        *(float4*)(Da + 0  * DSTR + c4) = z;
        *(float4*)(Da + 25 * DSTR + c4) = z;
        *(float4*)(Db + 0  * DSTR + c4) = z;
        *(float4*)(Db + 25 * DSTR + c4) = z;
    }
    __syncthreads();

    // ---- 14 full steps (ping-pong, ONE barrier each) + final step
#pragma unroll 1
    for (int s2 = 0; s2 < 7; ++s2) {
        STEP(0, Da, Db)
        STEP(0, Db, Da)
    }
    STEP(1, Da, Db)

    // ---- epilogue: waves 2..9 own exactly the 64 output rows (all in regs)
    if (wv >= 2 && wv <= 9) {
        const float inv15 = 1.0f / 15.0f;
#define EPI(I) {                                                                  \
        const int y = y0 + start + (I);                                           \
        size_t base = (size_t)img * (IMG*IMG) + (size_t)y * IMG + c4;             \
        float mn0 = sum##I.x*inv15, mn1 = sum##I.y*inv15;                         \
        float mn2 = sum##I.z*inv15, mn3 = sum##I.w*inv15;                         \
        float4 m4; m4.x=mn0; m4.y=mn1; m4.z=mn2; m4.w=mn3;                        \
        float4 v4;                                                               \
        v4.x = fmaxf(fmaf(-mn0, mn0, sq##I.x*inv15), 0.f);                        \
        v4.y = fmaxf(fmaf(-mn1, mn1, sq##I.y*inv15), 0.f);                        \
        v4.z = fmaxf(fmaf(-mn2, mn2, sq##I.z*inv15), 0.f);                        \
        v4.w = fmaxf(fmaf(-mn3, mn3, sq##I.w*inv15), 0.f);                        \
        float4 d4; d4.x = stg##I.x - dv##I.x; d4.y = stg##I.y - dv##I.y;          \
        d4.z = stg##I.z - dv##I.z; d4.w = stg##I.w - dv##I.w;                     \
        *(float4*)(out + 0*N_ELEM + base) = stg##I;                               \
        *(float4*)(out + 1*N_ELEM + base) = m4;                                   \
        *(float4*)(out + 2*N_ELEM + base) = v4;                                   \
        *(float4*)(out + 3*N_ELEM + base) = d4;                                   \
        *(float4*)(out + 4*N_ELEM + base) = d4; }
        EPI(0) EPI(1) EPI(2) EPI(3) EPI(4) EPI(5) EPI(6) EPI(7)
#undef EPI
    }
}

__global__ __launch_bounds__(NTHR, 3)   // 12-wave WG = 3 waves/EU; VGPR cap ~170
void cml_kernel(const float* __restrict__ drive,
                const float* __restrict__ Kl,
                float* __restrict__ out)
{
    __shared__ __align__(16) float lds[2 * DBUF];   // 53248 B
    const int bx  = blockIdx.x;
    const int img = bx >> 2;         // 0..127  (b*8 + c)
    const int ty  = bx & 3;          // 0..3   (64-row output bands, full width)
    const bool ey = (ty == 0) | (ty == 3);
    if (ey) run_tile<true >(drive, Kl, out, img, ty, lds);
    else    run_tile<false>(drive, Kl, out, img, ty, lds);
}

} // namespace

extern "C" void kernel_launch(void* const* d_in, const int* in_sizes, int n_in,
                              void* d_out, int out_size, void* d_ws, size_t ws_size,
                              hipStream_t stream) {
    const float* drive = (const float*)d_in[0];
    const float* Kl    = (const float*)d_in[1];
    float* out         = (float*)d_out;
    (void)in_sizes; (void)n_in; (void)out_size; (void)d_ws; (void)ws_size;

    dim3 grid(128 * 4);   // 128 images * 4 full-width bands
    dim3 block(NTHR);
    cml_kernel<<<grid, block, 0, stream>>>(drive, Kl, out);
}